// Round 3
// baseline (383509.790 us; speedup 1.0000x reference)
//
#include <hip/hip_runtime.h>
#include <cstddef>

#define LRC 0.001f
#define DEC 0.99f

// ---------------- workspace layout (float offsets) ----------------
static const size_t OFF_Z1P = 0;            // [32][2048]
static const size_t OFF_Z2P = 65536;        // [32][2048]
static const size_t OFF_Z2Q = 131072;
static const size_t OFF_Z3P = 196608;
static const size_t OFF_Z3Q = 262144;
static const size_t OFF_Z4P = 327680;       // [32][768]
static const size_t OFF_Z4Q = 352256;
static const size_t OFF_H1F = 376832;       // 2048 each below
static const size_t OFF_H1Q = 378880;
static const size_t OFF_H2F = 380928;
static const size_t OFF_H2Q = 382976;
static const size_t OFF_H3F = 385024;
static const size_t OFF_H3Q0 = 387072;      // h3q double buffer (even steps)
static const size_t OFF_D4F = 389120;       // 768
static const size_t OFF_D4Q = 389888;       // 768
static const size_t OFF_D3F = 390656;       // 2048
static const size_t OFF_D3Q = 392704;
static const size_t OFF_D2F = 394752;
static const size_t OFF_D2Q = 396800;
static const size_t OFF_D1F = 398848;
static const size_t OFF_D1Q = 400896;
static const size_t OFF_NSQ = 402944;       // 16: 0=x,1=h1,2=h2,3=h3,4=d4
static const size_t OFF_SL3 = 402960;       // 256 per-block |d3|^2 partials
static const size_t OFF_SL2 = 403216;
static const size_t OFF_SL1 = 403472;
static const size_t OFF_BUF = 403728;       // 2 (ping-pong EMA buffer)
static const size_t OFF_CONDF = 403730;     // 1 cond flag
static const size_t OFF_MSUM = 403732;      // [32][768]
static const size_t OFF_HA  = 428308;       // 1024*2048 (tail GEMM buffer)
static const size_t OFF_BAR = OFF_HA;       // 1024 ints carved from HA head (TTT-loop only)
static const size_t OFF_H3Q1 = OFF_HA + 1024; // 2048 floats (odd steps), also HA head
static const size_t OFF_HB  = 2525460;      // 1024*2048

__device__ inline void fma4(float4& a, float s, const float4& w) {
    a.x += s * w.x; a.y += s * w.y; a.z += s * w.z; a.w += s * w.w;
}

__device__ float block_reduce_512(float v) {
    __shared__ float red[512];
    int t = threadIdx.x;
    red[t] = v;
    __syncthreads();
    for (int s = 256; s > 0; s >>= 1) {
        if (t < s) red[t] += red[t + s];
        __syncthreads();
    }
    float r = red[0];
    __syncthreads();
    return r;
}

// ---- two-level monotonic grid barrier: 16 groups x 16 blocks, generation ----
__device__ inline void gbar(int* bar, int bi) {
    __syncthreads();
    if (threadIdx.x == 0) {
        __threadfence();
        int target = bi * 16 + 15;
        int g = (int)(blockIdx.x >> 4);
        int v = __hip_atomic_fetch_add(&bar[g * 16], 1, __ATOMIC_ACQ_REL, __HIP_MEMORY_SCOPE_AGENT);
        if (v == target) {
            int r = __hip_atomic_fetch_add(&bar[260], 1, __ATOMIC_ACQ_REL, __HIP_MEMORY_SCOPE_AGENT);
            if (r == target) {
                __hip_atomic_store(&bar[276], bi + 1, __ATOMIC_RELEASE, __HIP_MEMORY_SCOPE_AGENT);
            }
        }
        while (__hip_atomic_load(&bar[276], __ATOMIC_ACQUIRE, __HIP_MEMORY_SCOPE_AGENT) <= bi) {
            __builtin_amdgcn_s_sleep(2);
        }
        __threadfence();
    }
    __syncthreads();
}

// ---- fused [W update] + base+decayed matvec over K=2048 (phases B/C/D<96) ----
__device__ __forceinline__ void fwd2phase(int bblk, int tid, int w, int lane, float4* s4,
        const float* __restrict__ zinP, const float* __restrict__ zinQ,
        const float* __restrict__ bin, float* __restrict__ W, int Nout,
        float* __restrict__ zoutP, float* __restrict__ zoutQ,
        const float* __restrict__ uprev, const float* __restrict__ vprev,
        float* __restrict__ bl, bool upd) {
    float* sm = (float*)s4;
    float* hs = sm + 4096; float* hq = sm + 4160; float* us = sm + 4224;
    int p = bblk & 31, g = bblk >> 5;
    if (tid < 64) {
        int k = p * 64 + tid;
        float ssum = 0.f;
#pragma unroll 8
        for (int pp = 0; pp < 32; ++pp) ssum += zinP[pp * 2048 + k];
        float bv = bin[k];
        float h = fmaxf(ssum + bv, 0.f);
        float hqq;
        if (zinQ) {
            float sq = 0.f;
#pragma unroll 8
            for (int pp = 0; pp < 32; ++pp) sq += zinQ[pp * 2048 + k];
            hqq = fmaxf(DEC * (sq + bv), 0.f);
        } else {
            hqq = DEC * h;
        }
        hs[tid] = h; hq[tid] = hqq;
        us[tid] = upd ? (LRC * uprev[k]) : 0.f;
    }
    __syncthreads();
    int c0 = g * 256 + lane * 4;
    float4 vpv = make_float4(0.f, 0.f, 0.f, 0.f);
    if (upd) vpv = *(const float4*)(vprev + c0);
    float4 ap = make_float4(0.f, 0.f, 0.f, 0.f);
    float4 aq = make_float4(0.f, 0.f, 0.f, 0.f);
    if (upd) {
#pragma unroll
        for (int r = 0; r < 8; ++r) {
            int kk = w * 8 + r;
            float* wp = W + (size_t)(p * 64 + kk) * Nout + c0;
            float4 wv = *(const float4*)wp;
            float u = us[kk];
            wv.x = DEC * wv.x - u * vpv.x; wv.y = DEC * wv.y - u * vpv.y;
            wv.z = DEC * wv.z - u * vpv.z; wv.w = DEC * wv.w - u * vpv.w;
            *(float4*)wp = wv;
            fma4(ap, hs[kk], wv); fma4(aq, hq[kk], wv);
        }
    } else {
#pragma unroll
        for (int r = 0; r < 8; ++r) {
            int kk = w * 8 + r;
            const float4 wv = *(const float4*)(W + (size_t)(p * 64 + kk) * Nout + c0);
            fma4(ap, hs[kk], wv); fma4(aq, hq[kk], wv);
        }
    }
    if (upd && bblk == 0) {   // bias of THIS output layer, read next phase
        int c = tid * 4;
        if (c < Nout) {
            float4 dq = *(const float4*)(vprev + c);
            float4 bv = *(float4*)(bl + c);
            bv.x = DEC * bv.x - LRC * dq.x; bv.y = DEC * bv.y - LRC * dq.y;
            bv.z = DEC * bv.z - LRC * dq.z; bv.w = DEC * bv.w - LRC * dq.w;
            *(float4*)(bl + c) = bv;
        }
    }
    s4[w * 64 + lane] = ap;
    s4[512 + w * 64 + lane] = aq;
    __syncthreads();
    if (w == 0) {
        float4 sp = s4[lane], sq4 = s4[512 + lane];
#pragma unroll
        for (int q = 1; q < 8; ++q) {
            float4 r2 = s4[q * 64 + lane];       sp.x += r2.x; sp.y += r2.y; sp.z += r2.z; sp.w += r2.w;
            float4 r3 = s4[512 + q * 64 + lane]; sq4.x += r3.x; sq4.y += r3.y; sq4.z += r3.z; sq4.w += r3.w;
        }
        *(float4*)(zoutP + (size_t)p * Nout + c0) = sp;
        *(float4*)(zoutQ + (size_t)p * Nout + c0) = sq4;
    }
}

// ---- W^T backward phase (F/G), deltas staged from global ----
__device__ __forceinline__ void bwdphase(int bblk, int tid, int w, int lane,
        float* sm, float* sqw,
        const float* __restrict__ W, int K,
        const float* __restrict__ dinP, const float* __restrict__ dinQ,
        const float* __restrict__ hP, const float* __restrict__ hQ,
        float* __restrict__ doutP, float* __restrict__ doutQ, float* __restrict__ slot) {
    float* dsP = sm; float* dsQ = sm + 2048;
    for (int k = tid; k < K; k += 512) { dsP[k] = dinP[k]; dsQ[k] = dinQ[k]; }
    __syncthreads();
    int j = bblk * 8 + w;
    const float* row = W + (size_t)j * K;
    float ap = 0.f, aq = 0.f;
    for (int k4 = lane * 4; k4 < K; k4 += 256) {
        const float4 wv = *(const float4*)(row + k4);
        ap += wv.x * dsP[k4] + wv.y * dsP[k4 + 1] + wv.z * dsP[k4 + 2] + wv.w * dsP[k4 + 3];
        aq += wv.x * dsQ[k4] + wv.y * dsQ[k4 + 1] + wv.z * dsQ[k4 + 2] + wv.w * dsQ[k4 + 3];
    }
#pragma unroll
    for (int off = 32; off > 0; off >>= 1) {
        ap += __shfl_down(ap, off);
        aq += __shfl_down(aq, off);
    }
    if (lane == 0) {
        float dp = (hP[j] > 0.f) ? ap : 0.f;
        float dq = (hQ[j] > 0.f) ? DEC * aq : 0.f;
        doutP[j] = dp; doutQ[j] = dq; sqw[w] = dp * dp;
    }
    __syncthreads();
    if (tid == 0) {
        float t = 0.f;
#pragma unroll
        for (int q = 0; q < 8; ++q) t += sqw[q];
        slot[bblk] = t;
    }
}

// ---------------- the persistent TTT kernel: 1024 steps, 7 barriers/step ----------------
__global__ __launch_bounds__(512) void k_ttt(const float* __restrict__ x,
        float* __restrict__ W1, float* __restrict__ b1,
        float* __restrict__ W2, float* __restrict__ b2,
        float* __restrict__ W3, float* __restrict__ b3,
        float* __restrict__ W4, float* __restrict__ b4,
        float* __restrict__ wsf, const int* __restrict__ flag, int* __restrict__ bar) {
    if (*flag == 0) return;
    const int b = blockIdx.x, tid = threadIdx.x;
    const int w = tid >> 6, lane = tid & 63;
    __shared__ float4 s4[1408];     // 22.5 KB, aliased per phase
    __shared__ float cnd[4];
    __shared__ float sqw[8];
    float* sm = (float*)s4;
    int bi = 0;

    for (int s = 0; s < 1024; ++s) {
        const float* xt = x + (size_t)s * 3072;
        const float* xp = x + (size_t)(s > 0 ? s - 1 : 0) * 3072;
        float* h3q_cur = wsf + ((s & 1) ? OFF_H3Q1 : OFF_H3Q0);
        const float* h3q_prev = wsf + ((s & 1) ? OFF_H3Q0 : OFF_H3Q1);

        // ================= phase A: cond + fused W1/b1 update + z1 partials ========
        {
            int g = b >> 5, p = b & 31;
            int c0 = g * 256 + lane * 4;
            int kb = p * 24 + w * 3;
            float4 wv0 = *(const float4*)(W1 + (size_t)(kb + 0) * 2048 + c0);
            float4 wv1 = *(const float4*)(W1 + (size_t)(kb + 1) * 2048 + c0);
            float4 wv2 = *(const float4*)(W1 + (size_t)(kb + 2) * 2048 + c0);
            float a0 = xt[kb + 0], a1 = xt[kb + 1], a2 = xt[kb + 2];
            float4 dv = make_float4(0.f, 0.f, 0.f, 0.f);
            float u0 = 0.f, u1 = 0.f, u2 = 0.f;
            if (s > 0) {
                dv = *(const float4*)(wsf + OFF_D1Q + c0);
                u0 = LRC * xp[kb + 0]; u1 = LRC * xp[kb + 1]; u2 = LRC * xp[kb + 2];
            }
            float cond = 0.f;
            if (s > 0) {
                if (w < 3) {
                    const float* sl = wsf + (w == 0 ? OFF_SL1 : (w == 1 ? OFF_SL2 : OFF_SL3));
                    float v = sl[lane] + sl[lane + 64] + sl[lane + 128] + sl[lane + 192];
#pragma unroll
                    for (int off = 32; off > 0; off >>= 1) v += __shfl_down(v, off);
                    if (lane == 0) cnd[w] = v;
                }
                __syncthreads();
                float nd1 = sqrtf(cnd[0]), nd2 = sqrtf(cnd[1]), nd3 = sqrtf(cnd[2]);
                float nx = sqrtf(wsf[OFF_NSQ + 0]);
                float nh1 = sqrtf(wsf[OFF_NSQ + 1]);
                float nh2 = sqrtf(wsf[OFF_NSQ + 2]);
                float nh3 = sqrtf(wsf[OFF_NSQ + 3]);
                float nd4 = sqrtf(wsf[OFF_NSQ + 4]);
                float surprise = nx * nd1 + nd1 + nh1 * nd2 + nd2 + nh2 * nd3 + nd3 + nh3 * nd4 + nd4;
                float bufold = wsf[OFF_BUF + ((s - 1) & 1)];
                float bufnew = (s == 1) ? surprise : (0.9f * bufold + 0.1f * surprise);
                cond = (bufnew > 0.1f) ? 1.f : 0.f;
                if (b == 0 && tid == 0) {
                    wsf[OFF_BUF + (s & 1)] = bufnew;
                    wsf[OFF_CONDF] = cond;
                }
            } else {
                if (b == 0 && tid == 0) wsf[OFF_CONDF] = 0.f;
            }
            if (cond != 0.f) {
                wv0.x = DEC * wv0.x - u0 * dv.x; wv0.y = DEC * wv0.y - u0 * dv.y;
                wv0.z = DEC * wv0.z - u0 * dv.z; wv0.w = DEC * wv0.w - u0 * dv.w;
                wv1.x = DEC * wv1.x - u1 * dv.x; wv1.y = DEC * wv1.y - u1 * dv.y;
                wv1.z = DEC * wv1.z - u1 * dv.z; wv1.w = DEC * wv1.w - u1 * dv.w;
                wv2.x = DEC * wv2.x - u2 * dv.x; wv2.y = DEC * wv2.y - u2 * dv.y;
                wv2.z = DEC * wv2.z - u2 * dv.z; wv2.w = DEC * wv2.w - u2 * dv.w;
                *(float4*)(W1 + (size_t)(kb + 0) * 2048 + c0) = wv0;
                *(float4*)(W1 + (size_t)(kb + 1) * 2048 + c0) = wv1;
                *(float4*)(W1 + (size_t)(kb + 2) * 2048 + c0) = wv2;
                if (b == 0) {
                    int c = tid * 4;
                    float4 dq = *(const float4*)(wsf + OFF_D1Q + c);
                    float4 bv = *(float4*)(b1 + c);
                    bv.x = DEC * bv.x - LRC * dq.x; bv.y = DEC * bv.y - LRC * dq.y;
                    bv.z = DEC * bv.z - LRC * dq.z; bv.w = DEC * bv.w - LRC * dq.w;
                    *(float4*)(b1 + c) = bv;
                }
            }
            float4 acc = make_float4(0.f, 0.f, 0.f, 0.f);
            fma4(acc, a0, wv0); fma4(acc, a1, wv1); fma4(acc, a2, wv2);
            s4[w * 64 + lane] = acc;
            __syncthreads();
            if (w == 0) {
                float4 t = s4[lane];
#pragma unroll
                for (int q = 1; q < 8; ++q) {
                    float4 r2 = s4[q * 64 + lane];
                    t.x += r2.x; t.y += r2.y; t.z += r2.z; t.w += r2.w;
                }
                *(float4*)(wsf + OFF_Z1P + (size_t)p * 2048 + c0) = t;
            }
        }
        gbar(bar, bi++);

        // ================= phase B: layer 2 =================
        bool upd = (wsf[OFF_CONDF] != 0.f);
        fwd2phase(b, tid, w, lane, s4, wsf + OFF_Z1P, nullptr, b1, W2, 2048,
                  wsf + OFF_Z2P, wsf + OFF_Z2Q, wsf + OFF_H1Q, wsf + OFF_D2Q, b2, upd);
        gbar(bar, bi++);

        // ================= phase C: layer 3 =================
        fwd2phase(b, tid, w, lane, s4, wsf + OFF_Z2P, wsf + OFF_Z2Q, b2, W3, 2048,
                  wsf + OFF_Z3P, wsf + OFF_Z3Q, wsf + OFF_H2Q, wsf + OFF_D3Q, b3, upd);
        gbar(bar, bi++);

        // ================= phase D: layer 4 (96 blocks) + h finalize/norms (spares) ==
        if (b < 96) {
            fwd2phase(b, tid, w, lane, s4, wsf + OFF_Z3P, wsf + OFF_Z3Q, b3, W4, 768,
                      wsf + OFF_Z4P, wsf + OFF_Z4Q, h3q_prev, wsf + OFF_D4Q, b4, upd);
        } else {
            int idx = b - 96;
            if (idx < 16) {
                if (tid < 128) {
                    int e = idx * 128 + tid;
                    float ssum = 0.f;
#pragma unroll 8
                    for (int pp = 0; pp < 32; ++pp) ssum += wsf[OFF_Z1P + pp * 2048 + e];
                    float h = fmaxf(ssum + b1[e], 0.f);
                    wsf[OFF_H1F + e] = h;
                    wsf[OFF_H1Q + e] = DEC * h;
                }
            } else if (idx < 32) {
                if (tid < 128) {
                    int e = (idx - 16) * 128 + tid;
                    float ssum = 0.f, sq = 0.f;
#pragma unroll 8
                    for (int pp = 0; pp < 32; ++pp) {
                        ssum += wsf[OFF_Z2P + pp * 2048 + e];
                        sq += wsf[OFF_Z2Q + pp * 2048 + e];
                    }
                    float bv = b2[e];
                    wsf[OFF_H2F + e] = fmaxf(ssum + bv, 0.f);
                    wsf[OFF_H2Q + e] = fmaxf(DEC * (sq + bv), 0.f);
                }
            } else if (idx < 48) {
                if (tid < 128) {
                    int e = (idx - 32) * 128 + tid;
                    float ssum = 0.f, sq = 0.f;
#pragma unroll 8
                    for (int pp = 0; pp < 32; ++pp) {
                        ssum += wsf[OFF_Z3P + pp * 2048 + e];
                        sq += wsf[OFF_Z3Q + pp * 2048 + e];
                    }
                    float bv = b3[e];
                    wsf[OFF_H3F + e] = fmaxf(ssum + bv, 0.f);
                    h3q_cur[e] = fmaxf(DEC * (sq + bv), 0.f);
                }
            } else if (idx == 48) {          // ||x||^2
                float v = 0.f;
                for (int e = tid; e < 768; e += 512) { float xv = xt[e]; v += xv * xv; }
                float t = block_reduce_512(v);
                if (tid == 0) wsf[OFF_NSQ + 0] = t;
            } else if (idx == 49) {          // ||h1||^2
                float v = 0.f;
                for (int e = tid; e < 2048; e += 512) {
                    float ssum = 0.f;
#pragma unroll 8
                    for (int pp = 0; pp < 32; ++pp) ssum += wsf[OFF_Z1P + pp * 2048 + e];
                    float h = fmaxf(ssum + b1[e], 0.f);
                    v += h * h;
                }
                float t = block_reduce_512(v);
                if (tid == 0) wsf[OFF_NSQ + 1] = t;
            } else if (idx == 50) {          // ||h2||^2
                float v = 0.f;
                for (int e = tid; e < 2048; e += 512) {
                    float ssum = 0.f;
#pragma unroll 8
                    for (int pp = 0; pp < 32; ++pp) ssum += wsf[OFF_Z2P + pp * 2048 + e];
                    float h = fmaxf(ssum + b2[e], 0.f);
                    v += h * h;
                }
                float t = block_reduce_512(v);
                if (tid == 0) wsf[OFF_NSQ + 2] = t;
            } else if (idx == 51) {          // ||h3||^2
                float v = 0.f;
                for (int e = tid; e < 2048; e += 512) {
                    float ssum = 0.f;
#pragma unroll 8
                    for (int pp = 0; pp < 32; ++pp) ssum += wsf[OFF_Z3P + pp * 2048 + e];
                    float h = fmaxf(ssum + b3[e], 0.f);
                    v += h * h;
                }
                float t = block_reduce_512(v);
                if (tid == 0) wsf[OFF_NSQ + 3] = t;
            }
        }
        gbar(bar, bi++);

        // ================= phase E: bwd L4 (local d4 rebuild, no extra barrier) =====
        {
            float* d4P = sm; float* d4Q = sm + 768;
            for (int e = tid; e < 768; e += 512) {
                float sP = 0.f, sQ = 0.f;
#pragma unroll 8
                for (int pp = 0; pp < 32; ++pp) {
                    sP += wsf[OFF_Z4P + pp * 768 + e];
                    sQ += wsf[OFF_Z4Q + pp * 768 + e];
                }
                float bv = b4[e], tv = xt[e];
                d4P[e] = 2.f * ((sP + bv) - tv) * (1.f / 768.f);
                d4Q[e] = 2.f * (DEC * (sQ + bv) - tv) * (1.f / 768.f);
            }
            __syncthreads();
            int j = b * 8 + w;                     // 2048 rows of W4
            const float* row = W4 + (size_t)j * 768;
            float ap = 0.f, aq = 0.f;
#pragma unroll
            for (int k4 = lane * 4; k4 < 768; k4 += 256) {
                const float4 wv = *(const float4*)(row + k4);
                ap += wv.x * d4P[k4] + wv.y * d4P[k4 + 1] + wv.z * d4P[k4 + 2] + wv.w * d4P[k4 + 3];
                aq += wv.x * d4Q[k4] + wv.y * d4Q[k4 + 1] + wv.z * d4Q[k4 + 2] + wv.w * d4Q[k4 + 3];
            }
#pragma unroll
            for (int off = 32; off > 0; off >>= 1) {
                ap += __shfl_down(ap, off);
                aq += __shfl_down(aq, off);
            }
            if (lane == 0) {
                float dp = (wsf[OFF_H3F + j] > 0.f) ? ap : 0.f;
                float dq = (h3q_cur[j] > 0.f) ? DEC * aq : 0.f;
                wsf[OFF_D3F + j] = dp; wsf[OFF_D3Q + j] = dq; sqw[w] = dp * dp;
            }
            __syncthreads();
            if (tid == 0) {
                float t = 0.f;
#pragma unroll
                for (int q = 0; q < 8; ++q) t += sqw[q];
                wsf[OFF_SL3 + b] = t;
            }
            if (b == 0) {   // persist d4 + its norm for next step's cond / W4 update
                for (int e = tid; e < 768; e += 512) {
                    wsf[OFF_D4F + e] = d4P[e];
                    wsf[OFF_D4Q + e] = d4Q[e];
                }
                float v = 0.f;
                for (int e = tid; e < 768; e += 512) v += d4P[e] * d4P[e];
                float t = block_reduce_512(v);
                if (tid == 0) wsf[OFF_NSQ + 4] = t;
            }
        }
        gbar(bar, bi++);

        // ================= phase F: bwd L3 =================
        bwdphase(b, tid, w, lane, sm, sqw, W3, 2048,
                 wsf + OFF_D3F, wsf + OFF_D3Q, wsf + OFF_H2F, wsf + OFF_H2Q,
                 wsf + OFF_D2F, wsf + OFF_D2Q, wsf + OFF_SL2);
        gbar(bar, bi++);

        // ================= phase G: bwd L2 =================
        bwdphase(b, tid, w, lane, sm, sqw, W2, 2048,
                 wsf + OFF_D2F, wsf + OFF_D2Q, wsf + OFF_H1F, wsf + OFF_H1Q,
                 wsf + OFF_D1F, wsf + OFF_D1Q, wsf + OFF_SL1);
        gbar(bar, bi++);
    }
}

// ---------- post-loop: apply the LAST step's update once ----------
__global__ __launch_bounds__(512) void k_upd(int step, float* __restrict__ wsf,
                                             float* __restrict__ W1, float* __restrict__ b1,
                                             float* __restrict__ W2, float* __restrict__ b2,
                                             float* __restrict__ W3, float* __restrict__ b3,
                                             float* __restrict__ W4, float* __restrict__ b4,
                                             const float* __restrict__ xt,
                                             const int* __restrict__ flag) {
    if (*flag == 0) return;
    int tid = threadIdx.x, b = blockIdx.x;
    float s3 = block_reduce_512((tid < 256) ? wsf[OFF_SL3 + tid] : 0.f);
    float s2 = block_reduce_512((tid < 256) ? wsf[OFF_SL2 + tid] : 0.f);
    float s1 = block_reduce_512((tid < 256) ? wsf[OFF_SL1 + tid] : 0.f);
    __shared__ float condsh;
    if (tid == 0) {
        float nx = sqrtf(wsf[OFF_NSQ + 0]);
        float nh1 = sqrtf(wsf[OFF_NSQ + 1]);
        float nh2 = sqrtf(wsf[OFF_NSQ + 2]);
        float nh3 = sqrtf(wsf[OFF_NSQ + 3]);
        float nd4 = sqrtf(wsf[OFF_NSQ + 4]);
        float nd3 = sqrtf(s3), nd2 = sqrtf(s2), nd1 = sqrtf(s1);
        float surprise = nx * nd1 + nd1 + nh1 * nd2 + nd2 + nh2 * nd3 + nd3 + nh3 * nd4 + nd4;
        float bufold = wsf[OFF_BUF + (step & 1)];
        float bufnew = (step == 0) ? surprise : (0.9f * bufold + 0.1f * surprise);
        condsh = (bufnew > 0.1f) ? 1.f : 0.f;
    }
    __syncthreads();
    if (condsh == 0.f) return;

    const float* d1q = wsf + OFF_D1Q;
    const float* d2q = wsf + OFF_D2Q;
    const float* d3q = wsf + OFF_D3Q;
    const float* d4q = wsf + OFF_D4Q;
    const float* h1q = wsf + OFF_H1Q;
    const float* h2q = wsf + OFF_H2Q;
    const float* h3q = wsf + OFF_H3Q1;   // step 1023 is odd -> buffer 1
    int c = tid * 4;
    {
        float4 dv = *(const float4*)(d1q + c);
#pragma unroll
        for (int r = 0; r < 3; ++r) {
            int i = b * 3 + r;
            float u = LRC * xt[i];
            float4* wp = (float4*)(W1 + (size_t)i * 2048 + c);
            float4 wv = *wp;
            wv.x = DEC * wv.x - u * dv.x; wv.y = DEC * wv.y - u * dv.y;
            wv.z = DEC * wv.z - u * dv.z; wv.w = DEC * wv.w - u * dv.w;
            *wp = wv;
        }
    }
    {
        float4 dv = *(const float4*)(d2q + c);
#pragma unroll
        for (int r = 0; r < 8; ++r) {
            int i = b * 8 + r;
            float u = LRC * h1q[i];
            float4* wp = (float4*)(W2 + (size_t)i * 2048 + c);
            float4 wv = *wp;
            wv.x = DEC * wv.x - u * dv.x; wv.y = DEC * wv.y - u * dv.y;
            wv.z = DEC * wv.z - u * dv.z; wv.w = DEC * wv.w - u * dv.w;
            *wp = wv;
        }
    }
    {
        float4 dv = *(const float4*)(d3q + c);
#pragma unroll
        for (int r = 0; r < 8; ++r) {
            int i = b * 8 + r;
            float u = LRC * h2q[i];
            float4* wp = (float4*)(W3 + (size_t)i * 2048 + c);
            float4 wv = *wp;
            wv.x = DEC * wv.x - u * dv.x; wv.y = DEC * wv.y - u * dv.y;
            wv.z = DEC * wv.z - u * dv.z; wv.w = DEC * wv.w - u * dv.w;
            *wp = wv;
        }
    }
    if (tid < 192) {
        float4 dv = *(const float4*)(d4q + c);
#pragma unroll
        for (int r = 0; r < 8; ++r) {
            int i = b * 8 + r;
            float u = LRC * h3q[i];
            float4* wp = (float4*)(W4 + (size_t)i * 768 + c);
            float4 wv = *wp;
            wv.x = DEC * wv.x - u * dv.x; wv.y = DEC * wv.y - u * dv.y;
            wv.z = DEC * wv.z - u * dv.z; wv.w = DEC * wv.w - u * dv.w;
            *wp = wv;
        }
    }
    if (b == 0) {
        float4 dv = *(const float4*)(d1q + c);
        float4* bp = (float4*)(b1 + c);
        float4 bv = *bp;
        bv.x = DEC * bv.x - LRC * dv.x; bv.y = DEC * bv.y - LRC * dv.y;
        bv.z = DEC * bv.z - LRC * dv.z; bv.w = DEC * bv.w - LRC * dv.w;
        *bp = bv;
    } else if (b == 1) {
        float4 dv = *(const float4*)(d2q + c);
        float4* bp = (float4*)(b2 + c);
        float4 bv = *bp;
        bv.x = DEC * bv.x - LRC * dv.x; bv.y = DEC * bv.y - LRC * dv.y;
        bv.z = DEC * bv.z - LRC * dv.z; bv.w = DEC * bv.w - LRC * dv.w;
        *bp = bv;
    } else if (b == 2) {
        float4 dv = *(const float4*)(d3q + c);
        float4* bp = (float4*)(b3 + c);
        float4 bv = *bp;
        bv.x = DEC * bv.x - LRC * dv.x; bv.y = DEC * bv.y - LRC * dv.y;
        bv.z = DEC * bv.z - LRC * dv.z; bv.w = DEC * bv.w - LRC * dv.w;
        *bp = bv;
    } else if (b == 3 && tid < 192) {
        float4 dv = *(const float4*)(d4q + c);
        float4* bp = (float4*)(b4 + c);
        float4 bv = *bp;
        bv.x = DEC * bv.x - LRC * dv.x; bv.y = DEC * bv.y - LRC * dv.y;
        bv.z = DEC * bv.z - LRC * dv.z; bv.w = DEC * bv.w - LRC * dv.w;
        *bp = bv;
    }
}

// ---------- final batch forward: fp32 tiled GEMM C = act(A@W + bias) ----------
__global__ __launch_bounds__(256) void k_gemm(const float* __restrict__ A,
                                              const float* __restrict__ W,
                                              const float* __restrict__ bias,
                                              float* __restrict__ C,
                                              int M, int N, int K, int do_relu) {
    __shared__ float sA[16][64];
    __shared__ float sB[16][128];
    int bn = blockIdx.x, bm = blockIdx.y;
    int m0 = bm * 64, n0 = bn * 128;
    int tid = threadIdx.x;
    int tx = tid & 31, ty = tid >> 5;
    float acc[8][4];
#pragma unroll
    for (int i = 0; i < 8; ++i)
#pragma unroll
        for (int j = 0; j < 4; ++j) acc[i][j] = 0.f;

    for (int kt = 0; kt < K; kt += 16) {
        {
            int r = tid >> 2, cc = (tid & 3) * 4;
            const float4 a4 = *(const float4*)(A + (size_t)(m0 + r) * K + kt + cc);
            sA[cc + 0][r] = a4.x; sA[cc + 1][r] = a4.y; sA[cc + 2][r] = a4.z; sA[cc + 3][r] = a4.w;
        }
        {
            int r = tid >> 5, cc = (tid & 31) * 4;
            *(float4*)(&sB[r][cc]) = *(const float4*)(W + (size_t)(kt + r) * N + n0 + cc);
            *(float4*)(&sB[r + 8][cc]) = *(const float4*)(W + (size_t)(kt + r + 8) * N + n0 + cc);
        }
        __syncthreads();
#pragma unroll
        for (int k = 0; k < 16; ++k) {
            float av[8];
#pragma unroll
            for (int i = 0; i < 8; ++i) av[i] = sA[k][ty * 8 + i];
            float bx = sB[k][tx * 4 + 0], by = sB[k][tx * 4 + 1];
            float bz = sB[k][tx * 4 + 2], bw = sB[k][tx * 4 + 3];
#pragma unroll
            for (int i = 0; i < 8; ++i) {
                acc[i][0] += av[i] * bx; acc[i][1] += av[i] * by;
                acc[i][2] += av[i] * bz; acc[i][3] += av[i] * bw;
            }
        }
        __syncthreads();
    }
    float bx = bias[n0 + tx * 4 + 0], by = bias[n0 + tx * 4 + 1];
    float bz = bias[n0 + tx * 4 + 2], bw = bias[n0 + tx * 4 + 3];
#pragma unroll
    for (int i = 0; i < 8; ++i) {
        int m = m0 + ty * 8 + i;
        float4 v;
        v.x = acc[i][0] + bx; v.y = acc[i][1] + by;
        v.z = acc[i][2] + bz; v.w = acc[i][3] + bw;
        if (do_relu) {
            v.x = fmaxf(v.x, 0.f); v.y = fmaxf(v.y, 0.f);
            v.z = fmaxf(v.z, 0.f); v.w = fmaxf(v.w, 0.f);
        }
        *(float4*)(C + (size_t)m * N + n0 + tx * 4) = v;
    }
}

__global__ __launch_bounds__(128) void k_colsum(const float* __restrict__ Y,
                                                float* __restrict__ out) {
    int c = blockIdx.x * 128 + threadIdx.x;
    int r0 = blockIdx.y * 128;
    float s = 0.f;
    for (int r = 0; r < 128; ++r) s += Y[(size_t)(r0 + r) * 768 + c];
    out[blockIdx.y * 768 + c] = s;
}

__global__ __launch_bounds__(768) void k_out(const float* __restrict__ msum,
                                             float* __restrict__ out) {
    int c = threadIdx.x;
    float s = 0.f;
#pragma unroll
    for (int i = 0; i < 32; ++i) s += msum[i * 768 + c];
    out[c] = s * (1.f / 4096.f);
}

extern "C" void kernel_launch(void* const* d_in, const int* in_sizes, int n_in,
                              void* d_out, int out_size, void* d_ws, size_t ws_size,
                              hipStream_t stream) {
    const float* x = (const float*)d_in[0];
    float* W1 = (float*)d_in[1];
    float* b1 = (float*)d_in[2];
    float* W2 = (float*)d_in[3];
    float* b2 = (float*)d_in[4];
    float* W3 = (float*)d_in[5];
    float* b3 = (float*)d_in[6];
    float* W4 = (float*)d_in[7];
    float* b4 = (float*)d_in[8];
    const int* flag = (const int*)d_in[9];
    float* wsf = (float*)d_ws;
    int* bar = (int*)(wsf + OFF_BAR);

    // zero the barrier state (capture-legal async memset; region is tail-only)
    hipMemsetAsync((void*)bar, 0, 1024 * sizeof(int), stream);

    // ---- TTT scan: one persistent cooperative kernel, 1024 steps ----
    void* args[] = {(void*)&x, (void*)&W1, (void*)&b1, (void*)&W2, (void*)&b2,
                    (void*)&W3, (void*)&b3, (void*)&W4, (void*)&b4,
                    (void*)&wsf, (void*)&flag, (void*)&bar};
    hipLaunchCooperativeKernel((void*)k_ttt, dim3(256), dim3(512), args, 0, stream);

    // apply the final (step 1023) update once
    k_upd<<<256, 512, 0, stream>>>(1023, wsf, W1, b1, W2, b2, W3, b3, W4, b4,
                                   x + (size_t)1023 * 4 * 768, flag);

    // ---- final forward over all 4096 tokens, chunked by 1024, + mean ----
    float* HA = wsf + OFF_HA;
    float* HB = wsf + OFF_HB;
    for (int ch = 0; ch < 4; ++ch) {
        const float* Xc = x + (size_t)ch * 1024 * 768;
        k_gemm<<<dim3(16, 16), 256, 0, stream>>>(Xc, W1, b1, HA, 1024, 2048, 768, 1);
        k_gemm<<<dim3(16, 16), 256, 0, stream>>>(HA, W2, b2, HB, 1024, 2048, 2048, 1);
        k_gemm<<<dim3(16, 16), 256, 0, stream>>>(HB, W3, b3, HA, 1024, 2048, 2048, 1);
        k_gemm<<<dim3(6, 16), 256, 0, stream>>>(HA, W4, b4, HB, 1024, 768, 2048, 0);
        k_colsum<<<dim3(6, 8), 128, 0, stream>>>(HB, wsf + OFF_MSUM + (size_t)ch * 8 * 768);
    }
    k_out<<<1, 768, 0, stream>>>(wsf + OFF_MSUM, (float*)d_out);
}

// Round 5
// 72481.256 us; speedup vs baseline: 5.2912x; 5.2912x over previous
//
#include <hip/hip_runtime.h>
#include <cstddef>

#define LRC 0.001f
#define DEC 0.99f

typedef float vf4 __attribute__((ext_vector_type(4)));

// ---------------- workspace layout (float offsets) ----------------
// z-partials are TRANSPOSED: zT[k][32] -> one 128B line per k, batch-loadable.
static const size_t OFF_Z1T  = 0;           // [2048][32]
static const size_t OFF_Z2TP = 65536;       // [2048][32]
static const size_t OFF_Z2TQ = 131072;
static const size_t OFF_Z3TP = 196608;
static const size_t OFF_Z3TQ = 262144;
static const size_t OFF_Z4TP = 327680;      // [768][32]
static const size_t OFF_Z4TQ = 352256;
static const size_t OFF_H1F = 376832;       // 2048 each below
static const size_t OFF_H1Q = 378880;
static const size_t OFF_H2F = 380928;
static const size_t OFF_H2Q = 382976;
static const size_t OFF_H3F = 385024;
static const size_t OFF_H3Q0 = 387072;      // h3q double buffer (even steps)
static const size_t OFF_D4F = 389120;       // 768
static const size_t OFF_D4Q = 389888;       // 768
static const size_t OFF_D3F = 390656;       // 2048
static const size_t OFF_D3Q = 392704;
static const size_t OFF_D2F = 394752;
static const size_t OFF_D2Q = 396800;
static const size_t OFF_D1F = 398848;
static const size_t OFF_D1Q = 400896;
static const size_t OFF_NSQ = 402944;       // 16: 0=x,1=h1,2=h2,3=h3,4=d4
static const size_t OFF_SL3 = 402960;       // 256 per-block |d3|^2 partials
static const size_t OFF_SL2 = 403216;
static const size_t OFF_SL1 = 403472;
static const size_t OFF_BUF = 403728;       // 2 (ping-pong EMA buffer)
static const size_t OFF_CONDF = 403730;     // 1 cond flag
static const size_t OFF_MSUM = 403732;      // [32][768]
static const size_t OFF_HA  = 428308;       // 1024*2048 (tail GEMM buffer)
static const size_t OFF_BAR = OFF_HA;       // 1024 ints carved from HA head (TTT-loop only)
static const size_t OFF_H3Q1 = OFF_HA + 1024; // 2048 floats (odd steps), also HA head
static const size_t OFF_HB  = 2525460;      // 1024*2048

// ---------------- MALL-coherent access helpers (sc0 sc1 = bypass L1+L2) ------
struct V8 { vf4 v[8]; };

__device__ __forceinline__ float ld_cv(const float* p) {
    float v;
    asm volatile("global_load_dword %0, %1, off sc0 sc1\n\ts_waitcnt vmcnt(0)"
                 : "=&v"(v) : "v"(p) : "memory");
    return v;
}
__device__ __forceinline__ vf4 ld4_cv(const float* p) {
    vf4 v;
    asm volatile("global_load_dwordx4 %0, %1, off sc0 sc1\n\ts_waitcnt vmcnt(0)"
                 : "=&v"(v) : "v"(p) : "memory");
    return v;
}
// 32 consecutive floats (one 128B line) in one round trip
__device__ __forceinline__ V8 ld32_cv(const float* p) {
    V8 r;
    asm volatile(
        "global_load_dwordx4 %0, %8, off sc0 sc1\n\t"
        "global_load_dwordx4 %1, %8, off offset:16 sc0 sc1\n\t"
        "global_load_dwordx4 %2, %8, off offset:32 sc0 sc1\n\t"
        "global_load_dwordx4 %3, %8, off offset:48 sc0 sc1\n\t"
        "global_load_dwordx4 %4, %8, off offset:64 sc0 sc1\n\t"
        "global_load_dwordx4 %5, %8, off offset:80 sc0 sc1\n\t"
        "global_load_dwordx4 %6, %8, off offset:96 sc0 sc1\n\t"
        "global_load_dwordx4 %7, %8, off offset:112 sc0 sc1\n\t"
        "s_waitcnt vmcnt(0)"
        : "=&v"(r.v[0]), "=&v"(r.v[1]), "=&v"(r.v[2]), "=&v"(r.v[3]),
          "=&v"(r.v[4]), "=&v"(r.v[5]), "=&v"(r.v[6]), "=&v"(r.v[7])
        : "v"(p) : "memory");
    return r;
}
// 8 vf4 at 1KB stride: a 2048-wide row slice for one lane
__device__ __forceinline__ V8 ldrow_cv(const float* p) {
    const float* q = p + 1024;
    V8 r;
    asm volatile(
        "global_load_dwordx4 %0, %8, off sc0 sc1\n\t"
        "global_load_dwordx4 %1, %8, off offset:1024 sc0 sc1\n\t"
        "global_load_dwordx4 %2, %8, off offset:2048 sc0 sc1\n\t"
        "global_load_dwordx4 %3, %8, off offset:3072 sc0 sc1\n\t"
        "global_load_dwordx4 %4, %9, off sc0 sc1\n\t"
        "global_load_dwordx4 %5, %9, off offset:1024 sc0 sc1\n\t"
        "global_load_dwordx4 %6, %9, off offset:2048 sc0 sc1\n\t"
        "global_load_dwordx4 %7, %9, off offset:3072 sc0 sc1\n\t"
        "s_waitcnt vmcnt(0)"
        : "=&v"(r.v[0]), "=&v"(r.v[1]), "=&v"(r.v[2]), "=&v"(r.v[3]),
          "=&v"(r.v[4]), "=&v"(r.v[5]), "=&v"(r.v[6]), "=&v"(r.v[7])
        : "v"(p), "v"(q) : "memory");
    return r;
}
__device__ __forceinline__ void ldrow3_cv(const float* p, vf4& a, vf4& b, vf4& c) {
    asm volatile(
        "global_load_dwordx4 %0, %3, off sc0 sc1\n\t"
        "global_load_dwordx4 %1, %3, off offset:1024 sc0 sc1\n\t"
        "global_load_dwordx4 %2, %3, off offset:2048 sc0 sc1\n\t"
        "s_waitcnt vmcnt(0)"
        : "=&v"(a), "=&v"(b), "=&v"(c) : "v"(p) : "memory");
}
__device__ __forceinline__ void st_cv(float* p, float v) {
    asm volatile("global_store_dword %0, %1, off sc0 sc1" :: "v"(p), "v"(v) : "memory");
}
__device__ __forceinline__ void st_cv4(float* p, vf4 v) {
    asm volatile("global_store_dwordx4 %0, %1, off sc0 sc1" :: "v"(p), "v"(v) : "memory");
}
__device__ __forceinline__ float sum32(const V8& z) {
    float s = 0.f;
#pragma unroll
    for (int i = 0; i < 8; ++i) s += z.v[i].x + z.v[i].y + z.v[i].z + z.v[i].w;
    return s;
}

__device__ float block_reduce_512(float v) {
    __shared__ float red[512];
    int t = threadIdx.x;
    red[t] = v;
    __syncthreads();
    for (int s = 256; s > 0; s >>= 1) {
        if (t < s) red[t] += red[t + s];
        __syncthreads();
    }
    float r = red[0];
    __syncthreads();
    return r;
}

// ---- fence-free grid barrier: RELAXED atomics only (no L2 wb/inv emitted).
// Each thread drains its own vmem (sc1 stores ack at MALL) before arrival.
__device__ inline void gbar(int* bar, int bi) {
    asm volatile("s_waitcnt vmcnt(0) lgkmcnt(0)" ::: "memory");
    __syncthreads();
    if (threadIdx.x == 0) {
        int target = bi * 16 + 15;
        int g = (int)(blockIdx.x >> 4);
        int v = __hip_atomic_fetch_add(&bar[g * 16], 1, __ATOMIC_RELAXED, __HIP_MEMORY_SCOPE_AGENT);
        if (v == target) {
            int r = __hip_atomic_fetch_add(&bar[260], 1, __ATOMIC_RELAXED, __HIP_MEMORY_SCOPE_AGENT);
            if (r == target)
                __hip_atomic_store(&bar[276], bi + 1, __ATOMIC_RELAXED, __HIP_MEMORY_SCOPE_AGENT);
        }
        while (__hip_atomic_load(&bar[276], __ATOMIC_RELAXED, __HIP_MEMORY_SCOPE_AGENT) <= bi)
            __builtin_amdgcn_s_sleep(8);
    }
    __syncthreads();
}

// ---- fused [W update] + base+decayed matvec over K=2048 (phases B/C/D<96) ----
// Weight loads: NORMAL cached (same block owns+rewrites these lines every step).
// Weight stores: sc1 write-through. All cross-block data: sc1.
__device__ __forceinline__ void fwd2phase(int bblk, int tid, int w, int lane, vf4* s4,
        const float* zinTP, const float* zinTQ, const float* bin,
        float* W, int Nout, float* zoutTP, float* zoutTQ,
        const float* uprev, const float* vprev, float* bl, bool upd) {
    float* sm = (float*)s4;
    float* hs = sm + 4096; float* hq = sm + 4160; float* us = sm + 4224;
    int p = bblk & 31, g = bblk >> 5;
    if (tid < 64) {
        int k = p * 64 + tid;
        V8 zp = ld32_cv(zinTP + (size_t)k * 32);
        float ssum = sum32(zp);
        float bv = ld_cv(bin + k);
        float h = fmaxf(ssum + bv, 0.f);
        float hqq;
        if (zinTQ) {
            V8 zq = ld32_cv(zinTQ + (size_t)k * 32);
            hqq = fmaxf(DEC * (sum32(zq) + bv), 0.f);
        } else {
            hqq = DEC * h;
        }
        hs[tid] = h; hq[tid] = hqq;
        us[tid] = upd ? (LRC * ld_cv(uprev + k)) : 0.f;
    }
    __syncthreads();
    int c0 = g * 256 + lane * 4;
    vf4 vpv = {0.f, 0.f, 0.f, 0.f};
    if (upd) vpv = ld4_cv(vprev + c0);
    vf4 ap = {0.f, 0.f, 0.f, 0.f};
    vf4 aq = {0.f, 0.f, 0.f, 0.f};
    if (upd) {
#pragma unroll
        for (int r = 0; r < 8; ++r) {
            int kk = w * 8 + r;
            float* wp = W + (size_t)(p * 64 + kk) * Nout + c0;
            vf4 wv = *(const vf4*)wp;                // cached read (own line)
            wv = DEC * wv - us[kk] * vpv;
            st_cv4(wp, wv);                          // write-through to MALL
            ap += hs[kk] * wv; aq += hq[kk] * wv;
        }
    } else {
#pragma unroll
        for (int r = 0; r < 8; ++r) {
            int kk = w * 8 + r;
            const vf4 wv = *(const vf4*)(W + (size_t)(p * 64 + kk) * Nout + c0);
            ap += hs[kk] * wv; aq += hq[kk] * wv;
        }
    }
    if (upd && bblk == 0) {   // bias of THIS output layer, read next phase
        int c = tid * 4;
        if (c < Nout) {
            vf4 dq = ld4_cv(vprev + c);
            vf4 bv = ld4_cv(bl + c);
            st_cv4(bl + c, DEC * bv - LRC * dq);
        }
    }
    s4[w * 64 + lane] = ap;
    s4[512 + w * 64 + lane] = aq;
    __syncthreads();
    if (w == 0) {
        vf4 sp = s4[lane], sq4 = s4[512 + lane];
#pragma unroll
        for (int q = 1; q < 8; ++q) {
            sp += s4[q * 64 + lane];
            sq4 += s4[512 + q * 64 + lane];
        }
        st_cv(zoutTP + (size_t)(c0 + 0) * 32 + p, sp.x);
        st_cv(zoutTP + (size_t)(c0 + 1) * 32 + p, sp.y);
        st_cv(zoutTP + (size_t)(c0 + 2) * 32 + p, sp.z);
        st_cv(zoutTP + (size_t)(c0 + 3) * 32 + p, sp.w);
        st_cv(zoutTQ + (size_t)(c0 + 0) * 32 + p, sq4.x);
        st_cv(zoutTQ + (size_t)(c0 + 1) * 32 + p, sq4.y);
        st_cv(zoutTQ + (size_t)(c0 + 2) * 32 + p, sq4.z);
        st_cv(zoutTQ + (size_t)(c0 + 3) * 32 + p, sq4.w);
    }
}

// ---- W^T backward (F/G): wave-per-row, row read via sc1 (cross-XCD lines) ----
__device__ __forceinline__ void bwdphase(int bblk, int tid, int w, int lane,
        float* sm, float* sqw, const float* W,
        const float* dinP, const float* dinQ,
        const float* hP, const float* hQ,
        float* doutP, float* doutQ, float* slot) {
    float* dsP = sm; float* dsQ = sm + 2048;
    {
        int k4 = tid * 4;
        vf4 vP = ld4_cv(dinP + k4);
        vf4 vQ = ld4_cv(dinQ + k4);
        *(vf4*)(dsP + k4) = vP;
        *(vf4*)(dsQ + k4) = vQ;
    }
    __syncthreads();
    int j = bblk * 8 + w;
    V8 r = ldrow_cv(W + (size_t)j * 2048 + lane * 4);
    float ap = 0.f, aq = 0.f;
#pragma unroll
    for (int i = 0; i < 8; ++i) {
        int k0 = lane * 4 + i * 256;
        vf4 wv = r.v[i];
        ap += wv.x * dsP[k0] + wv.y * dsP[k0 + 1] + wv.z * dsP[k0 + 2] + wv.w * dsP[k0 + 3];
        aq += wv.x * dsQ[k0] + wv.y * dsQ[k0 + 1] + wv.z * dsQ[k0 + 2] + wv.w * dsQ[k0 + 3];
    }
#pragma unroll
    for (int off = 32; off > 0; off >>= 1) {
        ap += __shfl_down(ap, off);
        aq += __shfl_down(aq, off);
    }
    if (lane == 0) {
        float dp = (ld_cv(hP + j) > 0.f) ? ap : 0.f;
        float dq = (ld_cv(hQ + j) > 0.f) ? DEC * aq : 0.f;
        st_cv(doutP + j, dp); st_cv(doutQ + j, dq); sqw[w] = dp * dp;
    }
    __syncthreads();
    if (tid == 0) {
        float t = 0.f;
#pragma unroll
        for (int q = 0; q < 8; ++q) t += sqw[q];
        st_cv(slot + bblk, t);
    }
}

// ---------------- persistent TTT kernel: 1024 steps, 7 fence-free barriers/step --
__global__ __launch_bounds__(512) void k_ttt(const float* __restrict__ x,
        float* __restrict__ W1, float* __restrict__ b1,
        float* __restrict__ W2, float* __restrict__ b2,
        float* __restrict__ W3, float* __restrict__ b3,
        float* __restrict__ W4, float* __restrict__ b4,
        float* __restrict__ wsf, const int* __restrict__ flag, int* __restrict__ bar) {
    if (*flag == 0) return;
    const int b = blockIdx.x, tid = threadIdx.x;
    const int w = tid >> 6, lane = tid & 63;
    __shared__ vf4 s4[1408];     // 22.5 KB, aliased per phase
    __shared__ float cnd[12];
    __shared__ float sqw[8];
    __shared__ float updsh;
    float* sm = (float*)s4;
    int bi = 0;

    for (int s = 0; s < 1024; ++s) {
        const float* xt = x + (size_t)s * 3072;
        const float* xp = x + (size_t)(s > 0 ? s - 1 : 0) * 3072;
        float* h3q_cur = wsf + ((s & 1) ? OFF_H3Q1 : OFF_H3Q0);
        const float* h3q_prev = wsf + ((s & 1) ? OFF_H3Q0 : OFF_H3Q1);

        // ===== phase A: cond + fused W1/b1 update + z1 partials =====
        {
            int g = b >> 5, p = b & 31;
            int c0 = g * 256 + lane * 4;
            int kb = p * 24 + w * 3;
            vf4 wv0 = *(const vf4*)(W1 + (size_t)(kb + 0) * 2048 + c0);
            vf4 wv1 = *(const vf4*)(W1 + (size_t)(kb + 1) * 2048 + c0);
            vf4 wv2 = *(const vf4*)(W1 + (size_t)(kb + 2) * 2048 + c0);
            float a0 = xt[kb + 0], a1 = xt[kb + 1], a2 = xt[kb + 2];
            vf4 dv = {0.f, 0.f, 0.f, 0.f};
            float u0 = 0.f, u1 = 0.f, u2 = 0.f;
            float cond = 0.f;
            if (s > 0) {
                dv = ld4_cv(wsf + OFF_D1Q + c0);
                u0 = LRC * xp[kb + 0]; u1 = LRC * xp[kb + 1]; u2 = LRC * xp[kb + 2];
                if (w < 3) {
                    const float* sl = wsf + (w == 0 ? OFF_SL1 : (w == 1 ? OFF_SL2 : OFF_SL3));
                    vf4 v4 = ld4_cv(sl + lane * 4);
                    float v = v4.x + v4.y + v4.z + v4.w;
#pragma unroll
                    for (int off = 32; off > 0; off >>= 1) v += __shfl_down(v, off);
                    if (lane == 0) cnd[w] = v;
                } else if (w == 3 && lane < 6) {
                    cnd[3 + lane] = (lane < 5) ? ld_cv(wsf + OFF_NSQ + lane)
                                               : ld_cv(wsf + OFF_BUF + ((s - 1) & 1));
                }
                __syncthreads();
                float nd1 = sqrtf(cnd[0]), nd2 = sqrtf(cnd[1]), nd3 = sqrtf(cnd[2]);
                float nx = sqrtf(cnd[3]), nh1 = sqrtf(cnd[4]), nh2 = sqrtf(cnd[5]);
                float nh3 = sqrtf(cnd[6]), nd4 = sqrtf(cnd[7]);
                float bufold = cnd[8];
                float surprise = nx * nd1 + nd1 + nh1 * nd2 + nd2 + nh2 * nd3 + nd3 + nh3 * nd4 + nd4;
                float bufnew = (s == 1) ? surprise : (0.9f * bufold + 0.1f * surprise);
                cond = (bufnew > 0.1f) ? 1.f : 0.f;
                if (b == 0 && tid == 0) {
                    st_cv(wsf + OFF_BUF + (s & 1), bufnew);
                    st_cv(wsf + OFF_CONDF, cond);
                }
            } else {
                if (b == 0 && tid == 0) st_cv(wsf + OFF_CONDF, 0.f);
            }
            if (tid == 0) updsh = cond;
            if (cond != 0.f) {
                wv0 = DEC * wv0 - u0 * dv;
                wv1 = DEC * wv1 - u1 * dv;
                wv2 = DEC * wv2 - u2 * dv;
                st_cv4(W1 + (size_t)(kb + 0) * 2048 + c0, wv0);
                st_cv4(W1 + (size_t)(kb + 1) * 2048 + c0, wv1);
                st_cv4(W1 + (size_t)(kb + 2) * 2048 + c0, wv2);
                if (b == 0) {
                    int c = tid * 4;
                    vf4 dq = ld4_cv(wsf + OFF_D1Q + c);
                    vf4 bv = ld4_cv(b1 + c);
                    st_cv4(b1 + c, DEC * bv - LRC * dq);
                }
            }
            vf4 acc = a0 * wv0 + a1 * wv1 + a2 * wv2;
            s4[w * 64 + lane] = acc;
            __syncthreads();
            if (w == 0) {
                vf4 t = s4[lane];
#pragma unroll
                for (int q = 1; q < 8; ++q) t += s4[q * 64 + lane];
                st_cv(wsf + OFF_Z1T + (size_t)(c0 + 0) * 32 + p, t.x);
                st_cv(wsf + OFF_Z1T + (size_t)(c0 + 1) * 32 + p, t.y);
                st_cv(wsf + OFF_Z1T + (size_t)(c0 + 2) * 32 + p, t.z);
                st_cv(wsf + OFF_Z1T + (size_t)(c0 + 3) * 32 + p, t.w);
            }
        }
        gbar(bar, bi++);

        bool upd = (updsh != 0.f);   // uniform per step, computed identically by all blocks

        // ===== phase B: layer 2 =====
        fwd2phase(b, tid, w, lane, s4, wsf + OFF_Z1T, nullptr, b1, W2, 2048,
                  wsf + OFF_Z2TP, wsf + OFF_Z2TQ, wsf + OFF_H1Q, wsf + OFF_D2Q, b2, upd);
        gbar(bar, bi++);

        // ===== phase C: layer 3 =====
        fwd2phase(b, tid, w, lane, s4, wsf + OFF_Z2TP, wsf + OFF_Z2TQ, b2, W3, 2048,
                  wsf + OFF_Z3TP, wsf + OFF_Z3TQ, wsf + OFF_H2Q, wsf + OFF_D3Q, b3, upd);
        gbar(bar, bi++);

        // ===== phase D: layer 4 (96 blocks) + h finalize/norms (spares) =====
        if (b < 96) {
            fwd2phase(b, tid, w, lane, s4, wsf + OFF_Z3TP, wsf + OFF_Z3TQ, b3, W4, 768,
                      wsf + OFF_Z4TP, wsf + OFF_Z4TQ, h3q_prev, wsf + OFF_D4Q, b4, upd);
        } else {
            int idx = b - 96;
            if (idx < 16) {
                if (tid < 128) {
                    int e = idx * 128 + tid;
                    V8 z = ld32_cv(wsf + OFF_Z1T + (size_t)e * 32);
                    float h = fmaxf(sum32(z) + ld_cv(b1 + e), 0.f);
                    st_cv(wsf + OFF_H1F + e, h);
                    st_cv(wsf + OFF_H1Q + e, DEC * h);
                }
            } else if (idx < 32) {
                if (tid < 128) {
                    int e = (idx - 16) * 128 + tid;
                    V8 zp = ld32_cv(wsf + OFF_Z2TP + (size_t)e * 32);
                    V8 zq = ld32_cv(wsf + OFF_Z2TQ + (size_t)e * 32);
                    float bv = ld_cv(b2 + e);
                    st_cv(wsf + OFF_H2F + e, fmaxf(sum32(zp) + bv, 0.f));
                    st_cv(wsf + OFF_H2Q + e, fmaxf(DEC * (sum32(zq) + bv), 0.f));
                }
            } else if (idx < 48) {
                if (tid < 128) {
                    int e = (idx - 32) * 128 + tid;
                    V8 zp = ld32_cv(wsf + OFF_Z3TP + (size_t)e * 32);
                    V8 zq = ld32_cv(wsf + OFF_Z3TQ + (size_t)e * 32);
                    float bv = ld_cv(b3 + e);
                    st_cv(wsf + OFF_H3F + e, fmaxf(sum32(zp) + bv, 0.f));
                    st_cv(h3q_cur + e, fmaxf(DEC * (sum32(zq) + bv), 0.f));
                }
            } else if (idx == 48) {          // ||x||^2
                float v = 0.f;
                for (int e = tid; e < 768; e += 512) { float xv = xt[e]; v += xv * xv; }
                float t = block_reduce_512(v);
                if (tid == 0) st_cv(wsf + OFF_NSQ + 0, t);
            } else if (idx == 49) {          // ||h1||^2
                float v = 0.f;
                for (int e = tid; e < 2048; e += 512) {
                    V8 z = ld32_cv(wsf + OFF_Z1T + (size_t)e * 32);
                    float h = fmaxf(sum32(z) + ld_cv(b1 + e), 0.f);
                    v += h * h;
                }
                float t = block_reduce_512(v);
                if (tid == 0) st_cv(wsf + OFF_NSQ + 1, t);
            } else if (idx == 50) {          // ||h2||^2
                float v = 0.f;
                for (int e = tid; e < 2048; e += 512) {
                    V8 z = ld32_cv(wsf + OFF_Z2TP + (size_t)e * 32);
                    float h = fmaxf(sum32(z) + ld_cv(b2 + e), 0.f);
                    v += h * h;
                }
                float t = block_reduce_512(v);
                if (tid == 0) st_cv(wsf + OFF_NSQ + 2, t);
            } else if (idx == 51) {          // ||h3||^2
                float v = 0.f;
                for (int e = tid; e < 2048; e += 512) {
                    V8 z = ld32_cv(wsf + OFF_Z3TP + (size_t)e * 32);
                    float h = fmaxf(sum32(z) + ld_cv(b3 + e), 0.f);
                    v += h * h;
                }
                float t = block_reduce_512(v);
                if (tid == 0) st_cv(wsf + OFF_NSQ + 3, t);
            }
        }
        gbar(bar, bi++);

        // ===== phase E: bwd L4 (local d4 rebuild) =====
        {
            float* d4P = sm; float* d4Q = sm + 768;
            for (int e = tid; e < 768; e += 512) {
                V8 zp = ld32_cv(wsf + OFF_Z4TP + (size_t)e * 32);
                V8 zq = ld32_cv(wsf + OFF_Z4TQ + (size_t)e * 32);
                float bv = ld_cv(b4 + e), tv = xt[e];
                d4P[e] = 2.f * ((sum32(zp) + bv) - tv) * (1.f / 768.f);
                d4Q[e] = 2.f * (DEC * (sum32(zq) + bv) - tv) * (1.f / 768.f);
            }
            __syncthreads();
            int j = b * 8 + w;                     // 2048 rows of W4
            vf4 r0, r1, r2;
            ldrow3_cv(W4 + (size_t)j * 768 + lane * 4, r0, r1, r2);
            float ap = 0.f, aq = 0.f;
            {
                int k0 = lane * 4;
                ap += r0.x * d4P[k0] + r0.y * d4P[k0 + 1] + r0.z * d4P[k0 + 2] + r0.w * d4P[k0 + 3];
                aq += r0.x * d4Q[k0] + r0.y * d4Q[k0 + 1] + r0.z * d4Q[k0 + 2] + r0.w * d4Q[k0 + 3];
                k0 += 256;
                ap += r1.x * d4P[k0] + r1.y * d4P[k0 + 1] + r1.z * d4P[k0 + 2] + r1.w * d4P[k0 + 3];
                aq += r1.x * d4Q[k0] + r1.y * d4Q[k0 + 1] + r1.z * d4Q[k0 + 2] + r1.w * d4Q[k0 + 3];
                k0 += 256;
                ap += r2.x * d4P[k0] + r2.y * d4P[k0 + 1] + r2.z * d4P[k0 + 2] + r2.w * d4P[k0 + 3];
                aq += r2.x * d4Q[k0] + r2.y * d4Q[k0 + 1] + r2.z * d4Q[k0 + 2] + r2.w * d4Q[k0 + 3];
            }
#pragma unroll
            for (int off = 32; off > 0; off >>= 1) {
                ap += __shfl_down(ap, off);
                aq += __shfl_down(aq, off);
            }
            if (lane == 0) {
                float dp = (ld_cv(wsf + OFF_H3F + j) > 0.f) ? ap : 0.f;
                float dq = (ld_cv(h3q_cur + j) > 0.f) ? DEC * aq : 0.f;
                st_cv(wsf + OFF_D3F + j, dp); st_cv(wsf + OFF_D3Q + j, dq); sqw[w] = dp * dp;
            }
            __syncthreads();
            if (tid == 0) {
                float t = 0.f;
#pragma unroll
                for (int q = 0; q < 8; ++q) t += sqw[q];
                st_cv(wsf + OFF_SL3 + b, t);
            }
            if (b == 0) {   // persist d4 + its norm for next step
                float v = 0.f;
                for (int e = tid; e < 768; e += 512) {
                    st_cv(wsf + OFF_D4F + e, d4P[e]);
                    st_cv(wsf + OFF_D4Q + e, d4Q[e]);
                    v += d4P[e] * d4P[e];
                }
                float t = block_reduce_512(v);
                if (tid == 0) st_cv(wsf + OFF_NSQ + 4, t);
            }
        }
        gbar(bar, bi++);

        // ===== phase F: bwd L3 =====
        bwdphase(b, tid, w, lane, sm, sqw, W3,
                 wsf + OFF_D3F, wsf + OFF_D3Q, wsf + OFF_H2F, wsf + OFF_H2Q,
                 wsf + OFF_D2F, wsf + OFF_D2Q, wsf + OFF_SL2);
        gbar(bar, bi++);

        // ===== phase G: bwd L2 =====
        bwdphase(b, tid, w, lane, sm, sqw, W2,
                 wsf + OFF_D2F, wsf + OFF_D2Q, wsf + OFF_H1F, wsf + OFF_H1Q,
                 wsf + OFF_D1F, wsf + OFF_D1Q, wsf + OFF_SL1);
        gbar(bar, bi++);
    }
}

// ---------- post-loop: apply the LAST step's update once (normal kernel) ----------
__global__ __launch_bounds__(512) void k_upd(int step, float* __restrict__ wsf,
                                             float* __restrict__ W1, float* __restrict__ b1,
                                             float* __restrict__ W2, float* __restrict__ b2,
                                             float* __restrict__ W3, float* __restrict__ b3,
                                             float* __restrict__ W4, float* __restrict__ b4,
                                             const float* __restrict__ xt,
                                             const int* __restrict__ flag) {
    if (*flag == 0) return;
    int tid = threadIdx.x, b = blockIdx.x;
    float s3 = block_reduce_512((tid < 256) ? wsf[OFF_SL3 + tid] : 0.f);
    float s2 = block_reduce_512((tid < 256) ? wsf[OFF_SL2 + tid] : 0.f);
    float s1 = block_reduce_512((tid < 256) ? wsf[OFF_SL1 + tid] : 0.f);
    __shared__ float condsh;
    if (tid == 0) {
        float nx = sqrtf(wsf[OFF_NSQ + 0]);
        float nh1 = sqrtf(wsf[OFF_NSQ + 1]);
        float nh2 = sqrtf(wsf[OFF_NSQ + 2]);
        float nh3 = sqrtf(wsf[OFF_NSQ + 3]);
        float nd4 = sqrtf(wsf[OFF_NSQ + 4]);
        float nd3 = sqrtf(s3), nd2 = sqrtf(s2), nd1 = sqrtf(s1);
        float surprise = nx * nd1 + nd1 + nh1 * nd2 + nd2 + nh2 * nd3 + nd3 + nh3 * nd4 + nd4;
        float bufold = wsf[OFF_BUF + (step & 1)];
        float bufnew = (step == 0) ? surprise : (0.9f * bufold + 0.1f * surprise);
        condsh = (bufnew > 0.1f) ? 1.f : 0.f;
    }
    __syncthreads();
    if (condsh == 0.f) return;

    const float* d1q = wsf + OFF_D1Q;
    const float* d2q = wsf + OFF_D2Q;
    const float* d3q = wsf + OFF_D3Q;
    const float* d4q = wsf + OFF_D4Q;
    const float* h1q = wsf + OFF_H1Q;
    const float* h2q = wsf + OFF_H2Q;
    const float* h3q = wsf + OFF_H3Q1;   // step 1023 is odd -> buffer 1
    int c = tid * 4;
    {
        float4 dv = *(const float4*)(d1q + c);
#pragma unroll
        for (int r = 0; r < 3; ++r) {
            int i = b * 3 + r;
            float u = LRC * xt[i];
            float4* wp = (float4*)(W1 + (size_t)i * 2048 + c);
            float4 wv = *wp;
            wv.x = DEC * wv.x - u * dv.x; wv.y = DEC * wv.y - u * dv.y;
            wv.z = DEC * wv.z - u * dv.z; wv.w = DEC * wv.w - u * dv.w;
            *wp = wv;
        }
    }
    {
        float4 dv = *(const float4*)(d2q + c);
#pragma unroll
        for (int r = 0; r < 8; ++r) {
            int i = b * 8 + r;
            float u = LRC * h1q[i];
            float4* wp = (float4*)(W2 + (size_t)i * 2048 + c);
            float4 wv = *wp;
            wv.x = DEC * wv.x - u * dv.x; wv.y = DEC * wv.y - u * dv.y;
            wv.z = DEC * wv.z - u * dv.z; wv.w = DEC * wv.w - u * dv.w;
            *wp = wv;
        }
    }
    {
        float4 dv = *(const float4*)(d3q + c);
#pragma unroll
        for (int r = 0; r < 8; ++r) {
            int i = b * 8 + r;
            float u = LRC * h2q[i];
            float4* wp = (float4*)(W3 + (size_t)i * 2048 + c);
            float4 wv = *wp;
            wv.x = DEC * wv.x - u * dv.x; wv.y = DEC * wv.y - u * dv.y;
            wv.z = DEC * wv.z - u * dv.z; wv.w = DEC * wv.w - u * dv.w;
            *wp = wv;
        }
    }
    if (tid < 192) {
        float4 dv = *(const float4*)(d4q + c);
#pragma unroll
        for (int r = 0; r < 8; ++r) {
            int i = b * 8 + r;
            float u = LRC * h3q[i];
            float4* wp = (float4*)(W4 + (size_t)i * 768 + c);
            float4 wv = *wp;
            wv.x = DEC * wv.x - u * dv.x; wv.y = DEC * wv.y - u * dv.y;
            wv.z = DEC * wv.z - u * dv.z; wv.w = DEC * wv.w - u * dv.w;
            *wp = wv;
        }
    }
    if (b == 0) {
        float4 dv = *(const float4*)(d1q + c);
        float4* bp = (float4*)(b1 + c);
        float4 bv = *bp;
        bv.x = DEC * bv.x - LRC * dv.x; bv.y = DEC * bv.y - LRC * dv.y;
        bv.z = DEC * bv.z - LRC * dv.z; bv.w = DEC * bv.w - LRC * dv.w;
        *bp = bv;
    } else if (b == 1) {
        float4 dv = *(const float4*)(d2q + c);
        float4* bp = (float4*)(b2 + c);
        float4 bv = *bp;
        bv.x = DEC * bv.x - LRC * dv.x; bv.y = DEC * bv.y - LRC * dv.y;
        bv.z = DEC * bv.z - LRC * dv.z; bv.w = DEC * bv.w - LRC * dv.w;
        *bp = bv;
    } else if (b == 2) {
        float4 dv = *(const float4*)(d3q + c);
        float4* bp = (float4*)(b3 + c);
        float4 bv = *bp;
        bv.x = DEC * bv.x - LRC * dv.x; bv.y = DEC * bv.y - LRC * dv.y;
        bv.z = DEC * bv.z - LRC * dv.z; bv.w = DEC * bv.w - LRC * dv.w;
        *bp = bv;
    } else if (b == 3 && tid < 192) {
        float4 dv = *(const float4*)(d4q + c);
        float4* bp = (float4*)(b4 + c);
        float4 bv = *bp;
        bv.x = DEC * bv.x - LRC * dv.x; bv.y = DEC * bv.y - LRC * dv.y;
        bv.z = DEC * bv.z - LRC * dv.z; bv.w = DEC * bv.w - LRC * dv.w;
        *bp = bv;
    }
}

// ---------- final batch forward: fp32 tiled GEMM C = act(A@W + bias) ----------
__global__ __launch_bounds__(256) void k_gemm(const float* __restrict__ A,
                                              const float* __restrict__ W,
                                              const float* __restrict__ bias,
                                              float* __restrict__ C,
                                              int M, int N, int K, int do_relu) {
    __shared__ float sA[16][64];
    __shared__ float sB[16][128];
    int bn = blockIdx.x, bm = blockIdx.y;
    int m0 = bm * 64, n0 = bn * 128;
    int tid = threadIdx.x;
    int tx = tid & 31, ty = tid >> 5;
    float acc[8][4];
#pragma unroll
    for (int i = 0; i < 8; ++i)
#pragma unroll
        for (int j = 0; j < 4; ++j) acc[i][j] = 0.f;

    for (int kt = 0; kt < K; kt += 16) {
        {
            int r = tid >> 2, cc = (tid & 3) * 4;
            const float4 a4 = *(const float4*)(A + (size_t)(m0 + r) * K + kt + cc);
            sA[cc + 0][r] = a4.x; sA[cc + 1][r] = a4.y; sA[cc + 2][r] = a4.z; sA[cc + 3][r] = a4.w;
        }
        {
            int r = tid >> 5, cc = (tid & 31) * 4;
            *(float4*)(&sB[r][cc]) = *(const float4*)(W + (size_t)(kt + r) * N + n0 + cc);
            *(float4*)(&sB[r + 8][cc]) = *(const float4*)(W + (size_t)(kt + r + 8) * N + n0 + cc);
        }
        __syncthreads();
#pragma unroll
        for (int k = 0; k < 16; ++k) {
            float av[8];
#pragma unroll
            for (int i = 0; i < 8; ++i) av[i] = sA[k][ty * 8 + i];
            float bx = sB[k][tx * 4 + 0], by = sB[k][tx * 4 + 1];
            float bz = sB[k][tx * 4 + 2], bw = sB[k][tx * 4 + 3];
#pragma unroll
            for (int i = 0; i < 8; ++i) {
                acc[i][0] += av[i] * bx; acc[i][1] += av[i] * by;
                acc[i][2] += av[i] * bz; acc[i][3] += av[i] * bw;
            }
        }
        __syncthreads();
    }
    float bx = bias[n0 + tx * 4 + 0], by = bias[n0 + tx * 4 + 1];
    float bz = bias[n0 + tx * 4 + 2], bw = bias[n0 + tx * 4 + 3];
#pragma unroll
    for (int i = 0; i < 8; ++i) {
        int m = m0 + ty * 8 + i;
        float4 v;
        v.x = acc[i][0] + bx; v.y = acc[i][1] + by;
        v.z = acc[i][2] + bz; v.w = acc[i][3] + bw;
        if (do_relu) {
            v.x = fmaxf(v.x, 0.f); v.y = fmaxf(v.y, 0.f);
            v.z = fmaxf(v.z, 0.f); v.w = fmaxf(v.w, 0.f);
        }
        *(float4*)(C + (size_t)m * N + n0 + tx * 4) = v;
    }
}

__global__ __launch_bounds__(128) void k_colsum(const float* __restrict__ Y,
                                                float* __restrict__ out) {
    int c = blockIdx.x * 128 + threadIdx.x;
    int r0 = blockIdx.y * 128;
    float s = 0.f;
    for (int r = 0; r < 128; ++r) s += Y[(size_t)(r0 + r) * 768 + c];
    out[blockIdx.y * 768 + c] = s;
}

__global__ __launch_bounds__(768) void k_out(const float* __restrict__ msum,
                                             float* __restrict__ out) {
    int c = threadIdx.x;
    float s = 0.f;
#pragma unroll
    for (int i = 0; i < 32; ++i) s += msum[i * 768 + c];
    out[c] = s * (1.f / 4096.f);
}

extern "C" void kernel_launch(void* const* d_in, const int* in_sizes, int n_in,
                              void* d_out, int out_size, void* d_ws, size_t ws_size,
                              hipStream_t stream) {
    const float* x = (const float*)d_in[0];
    float* W1 = (float*)d_in[1];
    float* b1 = (float*)d_in[2];
    float* W2 = (float*)d_in[3];
    float* b2 = (float*)d_in[4];
    float* W3 = (float*)d_in[5];
    float* b3 = (float*)d_in[6];
    float* W4 = (float*)d_in[7];
    float* b4 = (float*)d_in[8];
    const int* flag = (const int*)d_in[9];
    float* wsf = (float*)d_ws;
    int* bar = (int*)(wsf + OFF_BAR);

    hipMemsetAsync((void*)bar, 0, 1024 * sizeof(int), stream);

    void* args[] = {(void*)&x, (void*)&W1, (void*)&b1, (void*)&W2, (void*)&b2,
                    (void*)&W3, (void*)&b3, (void*)&W4, (void*)&b4,
                    (void*)&wsf, (void*)&flag, (void*)&bar};
    hipLaunchCooperativeKernel((void*)k_ttt, dim3(256), dim3(512), args, 0, stream);

    k_upd<<<256, 512, 0, stream>>>(1023, wsf, W1, b1, W2, b2, W3, b3, W4, b4,
                                   x + (size_t)1023 * 4 * 768, flag);

    float* HA = wsf + OFF_HA;
    float* HB = wsf + OFF_HB;
    for (int ch = 0; ch < 4; ++ch) {
        const float* Xc = x + (size_t)ch * 1024 * 768;
        k_gemm<<<dim3(16, 16), 256, 0, stream>>>(Xc, W1, b1, HA, 1024, 2048, 768, 1);
        k_gemm<<<dim3(16, 16), 256, 0, stream>>>(HA, W2, b2, HB, 1024, 2048, 2048, 1);
        k_gemm<<<dim3(16, 16), 256, 0, stream>>>(HB, W3, b3, HA, 1024, 2048, 2048, 1);
        k_gemm<<<dim3(6, 16), 256, 0, stream>>>(HA, W4, b4, HB, 1024, 768, 2048, 0);
        k_colsum<<<dim3(6, 8), 128, 0, stream>>>(HB, wsf + OFF_MSUM + (size_t)ch * 8 * 768);
    }
    k_out<<<1, 768, 0, stream>>>(wsf + OFF_MSUM, (float*)d_out);
}